// Round 2
// baseline (3610.223 us; speedup 1.0000x reference)
//
#include <hip/hip_runtime.h>
#include <cstddef>
#include <cstdint>

#define BATCH 256
#define SEQL  128
#define BL    (BATCH * SEQL)   // 32768 rows of x
#define DIM   512              // 448 + 32 + 32 (== UNITS)
#define N3    1536             // 3 * UNITS
#define NCLS  53

typedef float f32x4 __attribute__((ext_vector_type(4)));
typedef short s16x8 __attribute__((ext_vector_type(8)));

__device__ __forceinline__ float bf2f(unsigned short u) {
    union { unsigned int i; float f; } v; v.i = ((unsigned int)u) << 16; return v.f;
}
__device__ __forceinline__ unsigned short f2bf(float f) {
    union { float f; unsigned int i; } v; v.f = f;
    unsigned int x = v.i;
    return (unsigned short)((x + 0x7fffu + ((x >> 16) & 1u)) >> 16);  // RNE
}
__device__ __forceinline__ float wave_sum(float v) {
    #pragma unroll
    for (int m = 32; m > 0; m >>= 1) v += __shfl_xor(v, m);
    return v;
}
__device__ __forceinline__ float wave_max(float v) {
    #pragma unroll
    for (int m = 32; m > 0; m >>= 1) v = fmaxf(v, __shfl_xor(v, m));
    return v;
}
__device__ __forceinline__ float sigmoidf(float x) { return 1.0f / (1.0f + expf(-x)); }

// ---------------------------------------------------------------------------
// Zero the initial GRU state (fp32 master + bf16 GEMM copy). 1024*512 elems.
__global__ __launch_bounds__(256) void zero_state_kernel(float* Hf, unsigned short* Hb) {
    int i = blockIdx.x * 256 + threadIdx.x;   // grid 2048 -> 524288
    Hf[i] = 0.0f;
    Hb[i] = 0;
}

// ---------------------------------------------------------------------------
// Transpose + bf16-cast a [512,1536] fp32 weight into Wt[1536,512] bf16
// (row-major N x K so MFMA B-fragments are contiguous 16B loads).
__global__ __launch_bounds__(256) void transpose_kernel(const float* __restrict__ W,
                                                        unsigned short* __restrict__ Wt) {
    __shared__ float tile[32][33];
    int tx = threadIdx.x & 31, ty = threadIdx.x >> 5;  // ty: 0..7
    int n0 = blockIdx.x * 32, k0 = blockIdx.y * 32;    // grid (48,16)
    #pragma unroll
    for (int r = 0; r < 4; ++r) {
        int kl = ty + r * 8;
        tile[kl][tx] = W[(size_t)(k0 + kl) * N3 + n0 + tx];
    }
    __syncthreads();
    #pragma unroll
    for (int r = 0; r < 4; ++r) {
        int nl = ty + r * 8;
        Wt[(size_t)(n0 + nl) * DIM + k0 + tx] = f2bf(tile[tx][nl]);
    }
}

// ---------------------------------------------------------------------------
// Gather word/pos embeddings -> X [32768, 512] bf16 (concat 448+32+32).
__global__ __launch_bounds__(64) void gather_kernel(const int* __restrict__ iw,
                                                    const int* __restrict__ ip1,
                                                    const int* __restrict__ ip2,
                                                    const float* __restrict__ wemb,
                                                    const float* __restrict__ pemb,
                                                    unsigned short* __restrict__ X) {
    int row = blockIdx.x;           // b*128 + l
    int tid = threadIdx.x;          // 64 threads x 8 elems
    int w = iw[row], p1 = ip1[row], p2 = ip2[row];
    int e0 = tid * 8;
    s16x8 o;
    #pragma unroll
    for (int j = 0; j < 8; ++j) {
        int e = e0 + j;
        float f;
        if (e < 448)      f = wemb[(size_t)w * 448 + e];
        else if (e < 480) f = pemb[p1 * 32 + (e - 448)];
        else              f = pemb[p2 * 32 + (e - 480)];
        o[j] = (short)f2bf(f);
    }
    *(s16x8*)(X + (size_t)row * DIM + e0) = o;
}

// ---------------------------------------------------------------------------
// One GRU timestep for all 4 runs (1024 state rows).
// Rows  0..255 : run A = GRU_f(x_f)  -> H1 slot t      , x at time t
// Rows 256..511: run C = GRU_f(x_b)  -> H2 slot t      , x at time 127-t
// Rows 512..767: run B = GRU_b(x_b)  -> H1 slot 127-t  , x at time 127-t
// Rows 768..1023:run D = GRU_b(x_f)  -> H2 slot 127-t  , x at time t
// Fused: rec = h @ rkernel (Bt) and xp = x @ kernel (Kt) in one K-loop.
// z,r gates: sums merge; h-gate keeps x-part and h-part separate (r * rh).
__global__ __launch_bounds__(64) void gru_step_kernel(
    const unsigned short* __restrict__ Hb_in, const float* __restrict__ Hf_in,
    unsigned short* __restrict__ Hb_out, float* __restrict__ Hf_out,
    const unsigned short* __restrict__ X,
    const unsigned short* __restrict__ Ktf, const unsigned short* __restrict__ Ktb,
    const unsigned short* __restrict__ Btf, const unsigned short* __restrict__ Btb,
    const float* __restrict__ gbf, const float* __restrict__ gbb,
    unsigned short* __restrict__ H1, unsigned short* __restrict__ H2, int t) {
    int lane = threadIdx.x;
    int row0 = blockIdx.x * 32;       // grid.x = 32  (1024 rows / 32)
    int u0   = blockIdx.y * 32;       // grid.y = 16  (512 u / 32)
    int runidx = row0 >> 8;

    const unsigned short* Bt = (row0 < 512) ? Btf : Btb;
    const unsigned short* Kt = (row0 < 512) ? Ktf : Ktb;
    const float* gb = (row0 < 512) ? gbf : gbb;
    const float* bi  = gb;           // input bias (row 0)
    const float* brp = gb + N3;      // recurrent bias (row 1)
    int tx = (runidx == 1 || runidx == 2) ? (127 - t) : t;   // x time index
    int th = (runidx >= 2) ? (127 - t) : t;                  // output slot
    unsigned short* Hdst = (runidx & 1) ? H2 : H1;

    int lr = lane & 15;
    int lk = (lane >> 4) * 8;

    f32x4 aZ[2][2], aR[2][2], aXH[2][2], aRH[2][2];
    #pragma unroll
    for (int mi = 0; mi < 2; ++mi)
        #pragma unroll
        for (int ni = 0; ni < 2; ++ni) {
            aZ[mi][ni] = (f32x4){0.f, 0.f, 0.f, 0.f};
            aR[mi][ni] = (f32x4){0.f, 0.f, 0.f, 0.f};
            aXH[mi][ni] = (f32x4){0.f, 0.f, 0.f, 0.f};
            aRH[mi][ni] = (f32x4){0.f, 0.f, 0.f, 0.f};
        }

    const unsigned short* ph0 = Hb_in + (size_t)(row0 + lr) * DIM + lk;
    const unsigned short* ph1 = ph0 + (size_t)16 * DIM;
    int b0 = (row0 + lr) & 255;
    int b1 = (row0 + 16 + lr) & 255;
    const unsigned short* px0 = X + ((size_t)b0 * SEQL + tx) * DIM + lk;
    const unsigned short* px1 = X + ((size_t)b1 * SEQL + tx) * DIM + lk;
    const unsigned short* pbt = Bt + lk;
    const unsigned short* pkt = Kt + lk;

    for (int kk = 0; kk < 16; ++kk) {
        int ko = kk * 32;
        s16x8 ah0 = *(const s16x8*)(ph0 + ko);
        s16x8 ah1 = *(const s16x8*)(ph1 + ko);
        s16x8 ax0 = *(const s16x8*)(px0 + ko);
        s16x8 ax1 = *(const s16x8*)(px1 + ko);
        #pragma unroll
        for (int ni = 0; ni < 2; ++ni) {
            size_t cz = (size_t)(u0 + ni * 16 + lr) * DIM + ko;
            s16x8 bz = *(const s16x8*)(pbt + cz);
            s16x8 br = *(const s16x8*)(pbt + cz + (size_t)512 * DIM);
            s16x8 bh = *(const s16x8*)(pbt + cz + (size_t)1024 * DIM);
            s16x8 kz = *(const s16x8*)(pkt + cz);
            s16x8 kr = *(const s16x8*)(pkt + cz + (size_t)512 * DIM);
            s16x8 kh = *(const s16x8*)(pkt + cz + (size_t)1024 * DIM);
            aZ[0][ni] = __builtin_amdgcn_mfma_f32_16x16x32_bf16(ah0, bz, aZ[0][ni], 0, 0, 0);
            aZ[0][ni] = __builtin_amdgcn_mfma_f32_16x16x32_bf16(ax0, kz, aZ[0][ni], 0, 0, 0);
            aZ[1][ni] = __builtin_amdgcn_mfma_f32_16x16x32_bf16(ah1, bz, aZ[1][ni], 0, 0, 0);
            aZ[1][ni] = __builtin_amdgcn_mfma_f32_16x16x32_bf16(ax1, kz, aZ[1][ni], 0, 0, 0);
            aR[0][ni] = __builtin_amdgcn_mfma_f32_16x16x32_bf16(ah0, br, aR[0][ni], 0, 0, 0);
            aR[0][ni] = __builtin_amdgcn_mfma_f32_16x16x32_bf16(ax0, kr, aR[0][ni], 0, 0, 0);
            aR[1][ni] = __builtin_amdgcn_mfma_f32_16x16x32_bf16(ah1, br, aR[1][ni], 0, 0, 0);
            aR[1][ni] = __builtin_amdgcn_mfma_f32_16x16x32_bf16(ax1, kr, aR[1][ni], 0, 0, 0);
            aRH[0][ni] = __builtin_amdgcn_mfma_f32_16x16x32_bf16(ah0, bh, aRH[0][ni], 0, 0, 0);
            aRH[1][ni] = __builtin_amdgcn_mfma_f32_16x16x32_bf16(ah1, bh, aRH[1][ni], 0, 0, 0);
            aXH[0][ni] = __builtin_amdgcn_mfma_f32_16x16x32_bf16(ax0, kh, aXH[0][ni], 0, 0, 0);
            aXH[1][ni] = __builtin_amdgcn_mfma_f32_16x16x32_bf16(ax1, kh, aXH[1][ni], 0, 0, 0);
        }
    }

    int rbase = (lane >> 4) * 4;
    #pragma unroll
    for (int ni = 0; ni < 2; ++ni) {
        int cu = u0 + ni * 16 + lr;
        float biz = bi[cu], bir = bi[512 + cu], bih = bi[1024 + cu];
        float brz = brp[cu], brr = brp[512 + cu], brh = brp[1024 + cu];
        #pragma unroll
        for (int mi = 0; mi < 2; ++mi) {
            #pragma unroll
            for (int reg = 0; reg < 4; ++reg) {
                int row = row0 + mi * 16 + rbase + reg;
                int b = row & 255;
                float z  = sigmoidf(aZ[mi][ni][reg] + biz + brz);
                float rg = sigmoidf(aR[mi][ni][reg] + bir + brr);
                float hh = tanhf(aXH[mi][ni][reg] + bih + rg * (aRH[mi][ni][reg] + brh));
                float hp = Hf_in[(size_t)row * DIM + cu];
                float hn = z * hp + (1.0f - z) * hh;
                Hf_out[(size_t)row * DIM + cu] = hn;
                unsigned short hb = f2bf(hn);
                Hb_out[(size_t)row * DIM + cu] = hb;
                Hdst[((size_t)b * SEQL + th) * DIM + cu] = hb;
            }
        }
    }
}

// ---------------------------------------------------------------------------
// scores[b,l] = sum_u tanh(h[b,l,u]) * attw[u]   (h = H1 + H2, bf16)
__global__ __launch_bounds__(64) void attn_scores_kernel(const unsigned short* __restrict__ H1,
                                                         const unsigned short* __restrict__ H2,
                                                         const float* __restrict__ attw,
                                                         float* __restrict__ scores) {
    int bl = blockIdx.x;   // grid 32768
    int lane = threadIdx.x;
    size_t base = (size_t)bl * DIM + lane * 8;
    s16x8 h1 = *(const s16x8*)(H1 + base);
    s16x8 h2 = *(const s16x8*)(H2 + base);
    float s = 0.0f;
    #pragma unroll
    for (int j = 0; j < 8; ++j) {
        float hv = bf2f((unsigned short)h1[j]) + bf2f((unsigned short)h2[j]);
        s += tanhf(hv) * attw[lane * 8 + j];
    }
    s = wave_sum(s);
    if (lane == 0) scores[bl] = s;
}

// alpha[b,:] = softmax over L=128
__global__ __launch_bounds__(64) void softmax_l_kernel(const float* __restrict__ scores,
                                                       float* __restrict__ alpha) {
    int b = blockIdx.x, lane = threadIdx.x;
    float s0 = scores[b * SEQL + lane];
    float s1 = scores[b * SEQL + 64 + lane];
    float m = wave_max(fmaxf(s0, s1));
    float e0 = expf(s0 - m), e1 = expf(s1 - m);
    float sum = wave_sum(e0 + e1);
    alpha[b * SEQL + lane] = e0 / sum;
    alpha[b * SEQL + 64 + lane] = e1 / sum;
}

// w_att_r[b,u] = sum_l alpha*h ; r = tanh(w); e[b] = sum_u r*sen_a*sen_r
__global__ __launch_bounds__(256) void attn_apply_kernel(const unsigned short* __restrict__ H1,
                                                         const unsigned short* __restrict__ H2,
                                                         const float* __restrict__ alpha,
                                                         const float* __restrict__ sena,
                                                         const float* __restrict__ senr,
                                                         float* __restrict__ rbuf,
                                                         float* __restrict__ ebuf) {
    int b = blockIdx.x, tid = threadIdx.x;
    __shared__ float al[SEQL];
    __shared__ float red[4];
    if (tid < SEQL) al[tid] = alpha[b * SEQL + tid];
    __syncthreads();
    float w0 = 0.0f, w1 = 0.0f;
    for (int l = 0; l < SEQL; ++l) {
        size_t base = ((size_t)b * SEQL + l) * DIM;
        float a = al[l];
        w0 += a * (bf2f(H1[base + tid]) + bf2f(H2[base + tid]));
        w1 += a * (bf2f(H1[base + 256 + tid]) + bf2f(H2[base + 256 + tid]));
    }
    float r0 = tanhf(w0), r1 = tanhf(w1);
    rbuf[(size_t)b * DIM + tid] = r0;
    rbuf[(size_t)b * DIM + 256 + tid] = r1;
    float p = r0 * sena[tid] * senr[tid] + r1 * sena[256 + tid] * senr[256 + tid];
    p = wave_sum(p);
    int wid = tid >> 6;
    if ((tid & 63) == 0) red[wid] = p;
    __syncthreads();
    if (tid == 0) ebuf[b] = red[0] + red[1] + red[2] + red[3];
}

// a = softmax over batch (256)
__global__ __launch_bounds__(64) void batch_softmax_kernel(const float* __restrict__ ebuf,
                                                           float* __restrict__ abuf) {
    int lane = threadIdx.x;
    float v0 = ebuf[lane], v1 = ebuf[64 + lane], v2 = ebuf[128 + lane], v3 = ebuf[192 + lane];
    float m = wave_max(fmaxf(fmaxf(v0, v1), fmaxf(v2, v3)));
    float e0 = expf(v0 - m), e1 = expf(v1 - m), e2 = expf(v2 - m), e3 = expf(v3 - m);
    float s = wave_sum(e0 + e1 + e2 + e3);
    abuf[lane] = e0 / s; abuf[64 + lane] = e1 / s;
    abuf[128 + lane] = e2 / s; abuf[192 + lane] = e3 / s;
}

// logits[b,c] = a[b]*(r[b]·sen_s[c]) + sen_d[c]; out = softmax over c
__global__ __launch_bounds__(64) void final_out_kernel(const float* __restrict__ rbuf,
                                                       const float* __restrict__ abuf,
                                                       const float* __restrict__ sens,
                                                       const float* __restrict__ send,
                                                       float* __restrict__ out) {
    int b = blockIdx.x, lane = threadIdx.x;
    __shared__ float lg[NCLS];
    float ab = abuf[b];
    float rv[8];
    #pragma unroll
    for (int j = 0; j < 8; ++j) rv[j] = rbuf[(size_t)b * DIM + j * 64 + lane];
    for (int c = 0; c < NCLS; ++c) {
        float d = 0.0f;
        #pragma unroll
        for (int j = 0; j < 8; ++j) d += rv[j] * sens[(size_t)c * DIM + j * 64 + lane];
        d = wave_sum(d);
        if (lane == 0) lg[c] = ab * d + send[c];
    }
    __syncthreads();
    float x = (lane < NCLS) ? lg[lane] : -3.0e38f;
    float m = wave_max(x);
    float ex = (lane < NCLS) ? expf(x - m) : 0.0f;
    float s = wave_sum(ex);
    if (lane < NCLS) out[b * NCLS + lane] = ex / s;
}

// ---------------------------------------------------------------------------
extern "C" void kernel_launch(void* const* d_in, const int* in_sizes, int n_in,
                              void* d_out, int out_size, void* d_ws, size_t ws_size,
                              hipStream_t stream) {
    (void)in_sizes; (void)n_in; (void)out_size; (void)ws_size;
    const int*   iw   = (const int*)d_in[0];
    const int*   ip1  = (const int*)d_in[1];
    const int*   ip2  = (const int*)d_in[2];
    const float* wemb = (const float*)d_in[3];
    const float* pemb = (const float*)d_in[4];
    const float* kf   = (const float*)d_in[5];
    const float* rf   = (const float*)d_in[6];
    const float* gbf  = (const float*)d_in[7];
    const float* kb   = (const float*)d_in[8];
    const float* rb   = (const float*)d_in[9];
    const float* gbb  = (const float*)d_in[10];
    const float* attw = (const float*)d_in[11];
    const float* sena = (const float*)d_in[12];
    const float* senr = (const float*)d_in[13];
    const float* send = (const float*)d_in[14];
    const float* sens = (const float*)d_in[15];
    float* out = (float*)d_out;

    char* p = (char*)d_ws;
    auto take = [&](size_t n) { char* q = p; p += ((n + 255) & ~(size_t)255); return q; };
    unsigned short* X    = (unsigned short*)take((size_t)BL * DIM * 2);       // 33.5 MB
    unsigned short* Ktf  = (unsigned short*)take((size_t)N3 * DIM * 2);
    unsigned short* Ktb  = (unsigned short*)take((size_t)N3 * DIM * 2);
    unsigned short* Btf  = (unsigned short*)take((size_t)N3 * DIM * 2);
    unsigned short* Btb  = (unsigned short*)take((size_t)N3 * DIM * 2);
    float*          Hf0  = (float*)take((size_t)1024 * DIM * 4);
    float*          Hf1  = (float*)take((size_t)1024 * DIM * 4);
    unsigned short* Hb0  = (unsigned short*)take((size_t)1024 * DIM * 2);
    unsigned short* Hb1  = (unsigned short*)take((size_t)1024 * DIM * 2);
    unsigned short* H1   = (unsigned short*)take((size_t)BL * DIM * 2);       // 33.5 MB
    unsigned short* H2   = (unsigned short*)take((size_t)BL * DIM * 2);       // 33.5 MB
    float* scores = (float*)take((size_t)BL * 4);
    float* alpha  = (float*)take((size_t)BL * 4);
    float* rbuf   = (float*)take((size_t)BATCH * DIM * 4);
    float* ebuf   = (float*)take((size_t)BATCH * 4);
    float* abuf   = (float*)take((size_t)BATCH * 4);

    zero_state_kernel<<<2048, 256, 0, stream>>>(Hf0, Hb0);
    transpose_kernel<<<dim3(48, 16), 256, 0, stream>>>(kf, Ktf);
    transpose_kernel<<<dim3(48, 16), 256, 0, stream>>>(kb, Ktb);
    transpose_kernel<<<dim3(48, 16), 256, 0, stream>>>(rf, Btf);
    transpose_kernel<<<dim3(48, 16), 256, 0, stream>>>(rb, Btb);
    gather_kernel<<<BL, 64, 0, stream>>>(iw, ip1, ip2, wemb, pemb, X);

    for (int t = 0; t < SEQL; ++t) {
        const unsigned short* hbi; const float* hfi;
        unsigned short* hbo; float* hfo;
        if (t & 1) { hbi = Hb1; hfi = Hf1; hbo = Hb0; hfo = Hf0; }
        else       { hbi = Hb0; hfi = Hf0; hbo = Hb1; hfo = Hf1; }
        gru_step_kernel<<<dim3(32, 16), 64, 0, stream>>>(
            hbi, hfi, hbo, hfo, X, Ktf, Ktb, Btf, Btb, gbf, gbb, H1, H2, t);
    }

    attn_scores_kernel<<<BL, 64, 0, stream>>>(H1, H2, attw, scores);
    softmax_l_kernel<<<BATCH, 64, 0, stream>>>(scores, alpha);
    attn_apply_kernel<<<BATCH, 256, 0, stream>>>(H1, H2, alpha, sena, senr, rbuf, ebuf);
    batch_softmax_kernel<<<1, 64, 0, stream>>>(ebuf, abuf);
    final_out_kernel<<<BATCH, 64, 0, stream>>>(rbuf, abuf, sens, send, out);
}

// Round 4
// 2536.301 us; speedup vs baseline: 1.4234x; 1.4234x over previous
//
#include <hip/hip_runtime.h>
#include <cstddef>
#include <cstdint>

#define BATCH 256
#define SEQL  128
#define BL    (BATCH * SEQL)   // 32768 rows of x
#define DIM   512              // 448 + 32 + 32 (== UNITS)
#define N3    1536             // 3 * UNITS
#define NCLS  53

typedef float f32x4 __attribute__((ext_vector_type(4)));
typedef short s16x8 __attribute__((ext_vector_type(8)));

__device__ __forceinline__ float bf2f(unsigned short u) {
    union { unsigned int i; float f; } v; v.i = ((unsigned int)u) << 16; return v.f;
}
__device__ __forceinline__ unsigned short f2bf(float f) {
    union { float f; unsigned int i; } v; v.f = f;
    unsigned int x = v.i;
    return (unsigned short)((x + 0x7fffu + ((x >> 16) & 1u)) >> 16);  // RNE
}
__device__ __forceinline__ float wave_sum(float v) {
    #pragma unroll
    for (int m = 32; m > 0; m >>= 1) v += __shfl_xor(v, m);
    return v;
}
__device__ __forceinline__ float wave_max(float v) {
    #pragma unroll
    for (int m = 32; m > 0; m >>= 1) v = fmaxf(v, __shfl_xor(v, m));
    return v;
}
__device__ __forceinline__ float sigmoidf(float x) { return 1.0f / (1.0f + expf(-x)); }

// ---------------------------------------------------------------------------
__global__ __launch_bounds__(256) void zero_state_kernel(float* Hf, unsigned short* Hb) {
    int i = blockIdx.x * 256 + threadIdx.x;   // grid 2048 -> 524288
    Hf[i] = 0.0f;
    Hb[i] = 0;
}

// ---------------------------------------------------------------------------
// Transpose + bf16-cast a [512,1536] fp32 weight into Wt[1536,512] bf16.
__global__ __launch_bounds__(256) void transpose_kernel(const float* __restrict__ W,
                                                        unsigned short* __restrict__ Wt) {
    __shared__ float tile[32][33];
    int tx = threadIdx.x & 31, ty = threadIdx.x >> 5;  // ty: 0..7
    int n0 = blockIdx.x * 32, k0 = blockIdx.y * 32;    // grid (48,16)
    #pragma unroll
    for (int r = 0; r < 4; ++r) {
        int kl = ty + r * 8;
        tile[kl][tx] = W[(size_t)(k0 + kl) * N3 + n0 + tx];
    }
    __syncthreads();
    #pragma unroll
    for (int r = 0; r < 4; ++r) {
        int nl = ty + r * 8;
        Wt[(size_t)(n0 + nl) * DIM + k0 + tx] = f2bf(tile[tx][nl]);
    }
}

// ---------------------------------------------------------------------------
// Gather word/pos embeddings -> X [32768, 512] bf16 (concat 448+32+32).
__global__ __launch_bounds__(64) void gather_kernel(const int* __restrict__ iw,
                                                    const int* __restrict__ ip1,
                                                    const int* __restrict__ ip2,
                                                    const float* __restrict__ wemb,
                                                    const float* __restrict__ pemb,
                                                    unsigned short* __restrict__ X) {
    int row = blockIdx.x;           // b*128 + l
    int tid = threadIdx.x;          // 64 threads x 8 elems
    int w = iw[row], p1 = ip1[row], p2 = ip2[row];
    int e0 = tid * 8;
    s16x8 o;
    #pragma unroll
    for (int j = 0; j < 8; ++j) {
        int e = e0 + j;
        float f;
        if (e < 448)      f = wemb[(size_t)w * 448 + e];
        else if (e < 480) f = pemb[p1 * 32 + (e - 448)];
        else              f = pemb[p2 * 32 + (e - 480)];
        o[j] = (short)f2bf(f);
    }
    *(s16x8*)(X + (size_t)row * DIM + e0) = o;
}

// ---------------------------------------------------------------------------
// XP[dir] = X @ kernel[dir] : [32768,512]x[512,1536] -> bf16, stored time-major:
// XP[(l*256 + b)*1536 + n]  (input row = b*128+l).
// Block: 256 thr, A-tile 64 rows x K=512 in LDS (XOR-swizzled), tile_n = 256.
// Waves 2x2: each wave 32 rows x 128 cols (2 mi x 8 ni of 16x16x32 MFMA).
__global__ __launch_bounds__(256, 2) void xp_gemm_kernel(const unsigned short* __restrict__ X,
                                                         const unsigned short* __restrict__ Ktf,
                                                         const unsigned short* __restrict__ Ktb,
                                                         unsigned short* __restrict__ XPf,
                                                         unsigned short* __restrict__ XPb) {
    const unsigned short* Kt = blockIdx.z ? Ktb : Ktf;
    unsigned short* XP = blockIdx.z ? XPb : XPf;
    int row0 = blockIdx.x * 64;     // grid.x = 512
    int n0   = blockIdx.y * 256;    // grid.y = 6

    __shared__ alignas(16) unsigned short As[64 * 512];   // 64 KB
    int tid = threadIdx.x;
    const char* src = (const char*)(X + (size_t)row0 * DIM);
    #pragma unroll
    for (int i = 0; i < 16; ++i) {
        int lin = (tid + i * 256) * 16;        // byte offset, contiguous global
        int row = lin >> 10;                   // 1024 B per row
        int swz = lin ^ ((row & 7) << 4);
        *(s16x8*)((char*)As + swz) = *(const s16x8*)(src + lin);
    }
    __syncthreads();

    int lane = tid & 63, wv = tid >> 6;
    int wr = wv >> 1, wc = wv & 1;            // wave rows wr*32.., cols wc*128..
    int lr = lane & 15, lk = (lane >> 4) * 8;

    f32x4 acc[2][8];
    #pragma unroll
    for (int mi = 0; mi < 2; ++mi)
        #pragma unroll
        for (int ni = 0; ni < 8; ++ni) acc[mi][ni] = (f32x4){0.f, 0.f, 0.f, 0.f};

    int r0 = wr * 32 + lr, r1 = r0 + 16;
    const unsigned short* bp = Kt + (size_t)(n0 + wc * 128 + lr) * DIM + lk;

    for (int kk = 0; kk < 16; ++kk) {
        int kb = kk * 64 + lk * 2;            // byte offset within a row
        s16x8 a0 = *(const s16x8*)((const char*)As + ((r0 * 1024 + kb) ^ ((r0 & 7) << 4)));
        s16x8 a1 = *(const s16x8*)((const char*)As + ((r1 * 1024 + kb) ^ ((r1 & 7) << 4)));
        #pragma unroll
        for (int ni = 0; ni < 8; ++ni) {
            s16x8 b = *(const s16x8*)(bp + (size_t)ni * 16 * DIM + kk * 32);
            acc[0][ni] = __builtin_amdgcn_mfma_f32_16x16x32_bf16(a0, b, acc[0][ni], 0, 0, 0);
            acc[1][ni] = __builtin_amdgcn_mfma_f32_16x16x32_bf16(a1, b, acc[1][ni], 0, 0, 0);
        }
    }

    int rbase = (lane >> 4) * 4;
    #pragma unroll
    for (int mi = 0; mi < 2; ++mi) {
        #pragma unroll
        for (int ni = 0; ni < 8; ++ni) {
            int n = n0 + wc * 128 + ni * 16 + lr;
            #pragma unroll
            for (int reg = 0; reg < 4; ++reg) {
                int gr = row0 + wr * 32 + mi * 16 + rbase + reg;   // = b*128 + l
                int b = gr >> 7, l = gr & 127;
                XP[((size_t)l * 256 + b) * N3 + n] = f2bf(acc[mi][ni][reg]);
            }
        }
    }
}

// ---------------------------------------------------------------------------
// One GRU timestep, recurrent part only (input projection comes from XP).
// 1024 state rows (4 runs x 256 batch). Block: 256 thr, 32 rows x 32 u.
// A-tile (32 rows x 512 K of Hb_in) staged in LDS with XOR swizzle; waves 2x2,
// each wave one 16x16 tile per gate panel (z, r, rh) = 48 MFMAs.
// Rows  0..255 : run A = GRU_f(x_f)  -> H1 slot t      , xp = XPf[t]
// Rows 256..511: run C = GRU_f(x_b)  -> H2 slot t      , xp = XPf[127-t]
// Rows 512..767: run B = GRU_b(x_b)  -> H1 slot 127-t  , xp = XPb[127-t]
// Rows 768..1023:run D = GRU_b(x_f)  -> H2 slot 127-t  , xp = XPb[t]
__global__ __launch_bounds__(256, 2) void gru_step2_kernel(
    const unsigned short* __restrict__ Hb_in, const float* __restrict__ Hf_in,
    unsigned short* __restrict__ Hb_out, float* __restrict__ Hf_out,
    const unsigned short* __restrict__ XPf, const unsigned short* __restrict__ XPb,
    const unsigned short* __restrict__ Btf, const unsigned short* __restrict__ Btb,
    const float* __restrict__ gbf, const float* __restrict__ gbb,
    unsigned short* __restrict__ H1, unsigned short* __restrict__ H2, int t) {
    int row0 = blockIdx.x * 32;       // grid.x = 32  (1024 rows / 32)
    int u0   = blockIdx.y * 32;       // grid.y = 16  (512 u / 32)
    int runidx = blockIdx.x >> 3;

    const unsigned short* Bt = (runidx < 2) ? Btf : Btb;
    const float* gb = (runidx < 2) ? gbf : gbb;
    const float* bi  = gb;            // input bias (row 0)
    const float* brp = gb + N3;       // recurrent bias (row 1)
    int tx = (runidx == 1 || runidx == 2) ? (127 - t) : t;   // xp time slice
    int th = (runidx >= 2) ? (127 - t) : t;                  // output slot
    unsigned short* Hdst = (runidx & 1) ? H2 : H1;
    const unsigned short* xps = ((runidx < 2) ? XPf : XPb) + (size_t)tx * 256 * N3;

    // --- stage A-tile: rows [row0, row0+32) of Hb_in, XOR-swizzled ---
    __shared__ alignas(16) unsigned short As[32 * 512];   // 32 KB
    int tid = threadIdx.x;
    const char* src = (const char*)(Hb_in + (size_t)row0 * DIM);
    #pragma unroll
    for (int i = 0; i < 8; ++i) {
        int lin = (tid + i * 256) * 16;
        int row = lin >> 10;
        int swz = lin ^ ((row & 7) << 4);
        *(s16x8*)((char*)As + swz) = *(const s16x8*)(src + lin);
    }
    __syncthreads();

    int lane = tid & 63, wv = tid >> 6;
    int wr = wv >> 1, wc = wv & 1;        // wave: rows wr*16.., u wc*16..
    int lr = lane & 15, lk = (lane >> 4) * 8;

    f32x4 aZ = (f32x4){0.f, 0.f, 0.f, 0.f};
    f32x4 aR = (f32x4){0.f, 0.f, 0.f, 0.f};
    f32x4 aH = (f32x4){0.f, 0.f, 0.f, 0.f};

    int ar = wr * 16 + lr;
    const unsigned short* bp = Bt + (size_t)(u0 + wc * 16 + lr) * DIM + lk;

    for (int kk = 0; kk < 16; ++kk) {
        int kb = kk * 64 + lk * 2;
        s16x8 af = *(const s16x8*)((const char*)As + ((ar * 1024 + kb) ^ ((ar & 7) << 4)));
        s16x8 bz = *(const s16x8*)(bp + kk * 32);
        s16x8 br = *(const s16x8*)(bp + (size_t)512 * DIM + kk * 32);
        s16x8 bh = *(const s16x8*)(bp + (size_t)1024 * DIM + kk * 32);
        aZ = __builtin_amdgcn_mfma_f32_16x16x32_bf16(af, bz, aZ, 0, 0, 0);
        aR = __builtin_amdgcn_mfma_f32_16x16x32_bf16(af, br, aR, 0, 0, 0);
        aH = __builtin_amdgcn_mfma_f32_16x16x32_bf16(af, bh, aH, 0, 0, 0);
    }

    int cu = u0 + wc * 16 + lr;
    float biz = bi[cu], bir = bi[512 + cu], bih = bi[1024 + cu];
    float brz = brp[cu], brr = brp[512 + cu], brh = brp[1024 + cu];
    int rbase = (lane >> 4) * 4;
    #pragma unroll
    for (int reg = 0; reg < 4; ++reg) {
        int row = row0 + wr * 16 + rbase + reg;
        int b = row & 255;
        const unsigned short* xpp = xps + (size_t)b * N3 + cu;
        float xz = bf2f(xpp[0]), xr = bf2f(xpp[512]), xh = bf2f(xpp[1024]);
        float z  = sigmoidf(xz + biz + aZ[reg] + brz);
        float rg = sigmoidf(xr + bir + aR[reg] + brr);
        float hh = tanhf(xh + bih + rg * (aH[reg] + brh));
        float hp = Hf_in[(size_t)row * DIM + cu];
        float hn = z * hp + (1.0f - z) * hh;
        Hf_out[(size_t)row * DIM + cu] = hn;
        unsigned short hb = f2bf(hn);
        Hb_out[(size_t)row * DIM + cu] = hb;
        Hdst[((size_t)b * SEQL + th) * DIM + cu] = hb;
    }
}

// ---------------------------------------------------------------------------
// scores[b,l] = sum_u tanh(h[b,l,u]) * attw[u]   (h = H1 + H2, bf16)
__global__ __launch_bounds__(64) void attn_scores_kernel(const unsigned short* __restrict__ H1,
                                                         const unsigned short* __restrict__ H2,
                                                         const float* __restrict__ attw,
                                                         float* __restrict__ scores) {
    int bl = blockIdx.x;   // grid 32768
    int lane = threadIdx.x;
    size_t base = (size_t)bl * DIM + lane * 8;
    s16x8 h1 = *(const s16x8*)(H1 + base);
    s16x8 h2 = *(const s16x8*)(H2 + base);
    float s = 0.0f;
    #pragma unroll
    for (int j = 0; j < 8; ++j) {
        float hv = bf2f((unsigned short)h1[j]) + bf2f((unsigned short)h2[j]);
        s += tanhf(hv) * attw[lane * 8 + j];
    }
    s = wave_sum(s);
    if (lane == 0) scores[bl] = s;
}

// alpha[b,:] = softmax over L=128
__global__ __launch_bounds__(64) void softmax_l_kernel(const float* __restrict__ scores,
                                                       float* __restrict__ alpha) {
    int b = blockIdx.x, lane = threadIdx.x;
    float s0 = scores[b * SEQL + lane];
    float s1 = scores[b * SEQL + 64 + lane];
    float m = wave_max(fmaxf(s0, s1));
    float e0 = expf(s0 - m), e1 = expf(s1 - m);
    float sum = wave_sum(e0 + e1);
    alpha[b * SEQL + lane] = e0 / sum;
    alpha[b * SEQL + 64 + lane] = e1 / sum;
}

// w_att_r[b,u] = sum_l alpha*h ; r = tanh(w); e[b] = sum_u r*sen_a*sen_r
__global__ __launch_bounds__(256) void attn_apply_kernel(const unsigned short* __restrict__ H1,
                                                         const unsigned short* __restrict__ H2,
                                                         const float* __restrict__ alpha,
                                                         const float* __restrict__ sena,
                                                         const float* __restrict__ senr,
                                                         float* __restrict__ rbuf,
                                                         float* __restrict__ ebuf) {
    int b = blockIdx.x, tid = threadIdx.x;
    __shared__ float al[SEQL];
    __shared__ float red[4];
    if (tid < SEQL) al[tid] = alpha[b * SEQL + tid];
    __syncthreads();
    float w0 = 0.0f, w1 = 0.0f;
    for (int l = 0; l < SEQL; ++l) {
        size_t base = ((size_t)b * SEQL + l) * DIM;
        float a = al[l];
        w0 += a * (bf2f(H1[base + tid]) + bf2f(H2[base + tid]));
        w1 += a * (bf2f(H1[base + 256 + tid]) + bf2f(H2[base + 256 + tid]));
    }
    float r0 = tanhf(w0), r1 = tanhf(w1);
    rbuf[(size_t)b * DIM + tid] = r0;
    rbuf[(size_t)b * DIM + 256 + tid] = r1;
    float p = r0 * sena[tid] * senr[tid] + r1 * sena[256 + tid] * senr[256 + tid];
    p = wave_sum(p);
    int wid = tid >> 6;
    if ((tid & 63) == 0) red[wid] = p;
    __syncthreads();
    if (tid == 0) ebuf[b] = red[0] + red[1] + red[2] + red[3];
}

// a = softmax over batch (256)
__global__ __launch_bounds__(64) void batch_softmax_kernel(const float* __restrict__ ebuf,
                                                           float* __restrict__ abuf) {
    int lane = threadIdx.x;
    float v0 = ebuf[lane], v1 = ebuf[64 + lane], v2 = ebuf[128 + lane], v3 = ebuf[192 + lane];
    float m = wave_max(fmaxf(fmaxf(v0, v1), fmaxf(v2, v3)));
    float e0 = expf(v0 - m), e1 = expf(v1 - m), e2 = expf(v2 - m), e3 = expf(v3 - m);
    float s = wave_sum(e0 + e1 + e2 + e3);
    abuf[lane] = e0 / s; abuf[64 + lane] = e1 / s;
    abuf[128 + lane] = e2 / s; abuf[192 + lane] = e3 / s;
}

// logits[b,c] = a[b]*(r[b]·sen_s[c]) + sen_d[c]; out = softmax over c
__global__ __launch_bounds__(64) void final_out_kernel(const float* __restrict__ rbuf,
                                                       const float* __restrict__ abuf,
                                                       const float* __restrict__ sens,
                                                       const float* __restrict__ send,
                                                       float* __restrict__ out) {
    int b = blockIdx.x, lane = threadIdx.x;
    __shared__ float lg[NCLS];
    float ab = abuf[b];
    float rv[8];
    #pragma unroll
    for (int j = 0; j < 8; ++j) rv[j] = rbuf[(size_t)b * DIM + j * 64 + lane];
    for (int c = 0; c < NCLS; ++c) {
        float d = 0.0f;
        #pragma unroll
        for (int j = 0; j < 8; ++j) d += rv[j] * sens[(size_t)c * DIM + j * 64 + lane];
        d = wave_sum(d);
        if (lane == 0) lg[c] = ab * d + send[c];
    }
    __syncthreads();
    float x = (lane < NCLS) ? lg[lane] : -3.0e38f;
    float m = wave_max(x);
    float ex = (lane < NCLS) ? expf(x - m) : 0.0f;
    float s = wave_sum(ex);
    if (lane < NCLS) out[b * NCLS + lane] = ex / s;
}

// ---------------------------------------------------------------------------
extern "C" void kernel_launch(void* const* d_in, const int* in_sizes, int n_in,
                              void* d_out, int out_size, void* d_ws, size_t ws_size,
                              hipStream_t stream) {
    (void)in_sizes; (void)n_in; (void)out_size; (void)ws_size;
    const int*   iw   = (const int*)d_in[0];
    const int*   ip1  = (const int*)d_in[1];
    const int*   ip2  = (const int*)d_in[2];
    const float* wemb = (const float*)d_in[3];
    const float* pemb = (const float*)d_in[4];
    const float* kf   = (const float*)d_in[5];
    const float* rf   = (const float*)d_in[6];
    const float* gbf  = (const float*)d_in[7];
    const float* kb   = (const float*)d_in[8];
    const float* rb   = (const float*)d_in[9];
    const float* gbb  = (const float*)d_in[10];
    const float* attw = (const float*)d_in[11];
    const float* sena = (const float*)d_in[12];
    const float* senr = (const float*)d_in[13];
    const float* send = (const float*)d_in[14];
    const float* sens = (const float*)d_in[15];
    float* out = (float*)d_out;

    char* p = (char*)d_ws;
    auto take = [&](size_t n) { char* q = p; p += ((n + 255) & ~(size_t)255); return q; };
    unsigned short* X    = (unsigned short*)take((size_t)BL * DIM * 2);       // 33.5 MB
    unsigned short* Ktf  = (unsigned short*)take((size_t)N3 * DIM * 2);
    unsigned short* Ktb  = (unsigned short*)take((size_t)N3 * DIM * 2);
    unsigned short* Btf  = (unsigned short*)take((size_t)N3 * DIM * 2);
    unsigned short* Btb  = (unsigned short*)take((size_t)N3 * DIM * 2);
    float*          Hf0  = (float*)take((size_t)1024 * DIM * 4);
    float*          Hf1  = (float*)take((size_t)1024 * DIM * 4);
    unsigned short* Hb0  = (unsigned short*)take((size_t)1024 * DIM * 2);
    unsigned short* Hb1  = (unsigned short*)take((size_t)1024 * DIM * 2);
    unsigned short* XPf  = (unsigned short*)take((size_t)BL * N3 * 2);        // 100.7 MB
    unsigned short* XPb  = (unsigned short*)take((size_t)BL * N3 * 2);        // 100.7 MB
    unsigned short* H1   = (unsigned short*)take((size_t)BL * DIM * 2);       // 33.5 MB
    unsigned short* H2   = (unsigned short*)take((size_t)BL * DIM * 2);       // 33.5 MB
    float* scores = (float*)take((size_t)BL * 4);
    float* alpha  = (float*)take((size_t)BL * 4);
    float* rbuf   = (float*)take((size_t)BATCH * DIM * 4);
    float* ebuf   = (float*)take((size_t)BATCH * 4);
    float* abuf   = (float*)take((size_t)BATCH * 4);

    zero_state_kernel<<<2048, 256, 0, stream>>>(Hf0, Hb0);
    transpose_kernel<<<dim3(48, 16), 256, 0, stream>>>(kf, Ktf);
    transpose_kernel<<<dim3(48, 16), 256, 0, stream>>>(kb, Ktb);
    transpose_kernel<<<dim3(48, 16), 256, 0, stream>>>(rf, Btf);
    transpose_kernel<<<dim3(48, 16), 256, 0, stream>>>(rb, Btb);
    gather_kernel<<<BL, 64, 0, stream>>>(iw, ip1, ip2, wemb, pemb, X);

    xp_gemm_kernel<<<dim3(512, 6, 2), 256, 0, stream>>>(X, Ktf, Ktb, XPf, XPb);

    for (int t = 0; t < SEQL; ++t) {
        const unsigned short* hbi; const float* hfi;
        unsigned short* hbo; float* hfo;
        if (t & 1) { hbi = Hb1; hfi = Hf1; hbo = Hb0; hfo = Hf0; }
        else       { hbi = Hb0; hfi = Hf0; hbo = Hb1; hfo = Hf1; }
        gru_step2_kernel<<<dim3(32, 16), 256, 0, stream>>>(
            hbi, hfi, hbo, hfo, XPf, XPb, Btf, Btb, gbf, gbb, H1, H2, t);
    }

    attn_scores_kernel<<<BL, 64, 0, stream>>>(H1, H2, attw, scores);
    softmax_l_kernel<<<BATCH, 64, 0, stream>>>(scores, alpha);
    attn_apply_kernel<<<BATCH, 256, 0, stream>>>(H1, H2, alpha, sena, senr, rbuf, ebuf);
    batch_softmax_kernel<<<1, 64, 0, stream>>>(ebuf, abuf);
    final_out_kernel<<<BATCH, 64, 0, stream>>>(rbuf, abuf, sens, send, out);
}